// Round 5
// baseline (204.691 us; speedup 1.0000x reference)
//
#include <hip/hip_runtime.h>
#include <hip/hip_bf16.h>

#define NN 50000
#define EE 800000
#define FF 144
#define CVTBLK 1758      // ceil(NN*FF/16/256)
#define ECHK 8192        // edges per partition block
#define NBE 98           // ceil(EE/ECHK)
#define NBKT_REAL 391    // row buckets of 128 rows (covers 50048)
#define NBUCKET 392      // + 1 self-loop bucket
#define WGRID 284        // ceil(3*144*168/256)
#define HM (NBUCKET * NBE)   // 38416 histogram entries
#define SCANBLK 151      // ceil(HM/256)

typedef __hip_bfloat16 bf16;
typedef __attribute__((ext_vector_type(8))) short short8;
typedef __attribute__((ext_vector_type(4))) float floatx4;
typedef __attribute__((ext_vector_type(2))) float float2v;

__device__ inline float blo(unsigned x) { return __uint_as_float(x << 16); }
__device__ inline float bhi(unsigned x) { return __uint_as_float(x & 0xffff0000u); }

// ---- fp8 e4m3 pack/unpack (gfx950 OCP) ----
__device__ inline void dec4fma(float* a, float l, unsigned d) {
    float2v p0 = __builtin_amdgcn_cvt_pk_f32_fp8((int)d, false);
    float2v p1 = __builtin_amdgcn_cvt_pk_f32_fp8((int)d, true);
    a[0] = fmaf(l, p0.x, a[0]);
    a[1] = fmaf(l, p0.y, a[1]);
    a[2] = fmaf(l, p1.x, a[2]);
    a[3] = fmaf(l, p1.y, a[3]);
}
__device__ inline void fma16q(float* a, float l, uint4 u) {
    dec4fma(a + 0, l, u.x);
    dec4fma(a + 4, l, u.y);
    dec4fma(a + 8, l, u.z);
    dec4fma(a + 12, l, u.w);
}
__device__ inline unsigned enc4(float a, float b, float c, float d) {
    int w = __builtin_amdgcn_cvt_pk_fp8_f32(a, b, 0, false);
    w = __builtin_amdgcn_cvt_pk_fp8_f32(c, d, w, true);
    return (unsigned)w;
}

__device__ inline void load_edge(const int* ei, int e, int flag, int& r, int& c) {
    if (flag) { r = ei[2 * e]; c = ei[2 * EE + 2 * e]; }
    else      { r = ei[e];     c = ei[EE + e]; }
}

// ---------------- fused A: cvt(x) | detect+pack+bucket-hist(edges) | cvt+fold(W) ----------------
// Blocks [0,CVTBLK): x fp32 -> bf16 + fp8.
// Blocks [CVTBLK, +NBE): self-detect edge_index layout on own chunk (OR of odd words),
//   pack edges into u64 items {row:16|col:16|w_fp32:32}, LDS histogram over 392
//   row-buckets (bucket = row>>7; self-loops -> 391). ZERO global atomics.
// Blocks [CVTBLK+NBE, +WGRID): W fp32 -> bf16 FOLDED (W0-W2, W1, 2*W2), transposed
//   padded wtb[ph][o][i].

__global__ void fusedA_k(const float* __restrict__ x, bf16* __restrict__ xb,
                         unsigned char* __restrict__ xq,
                         const int* __restrict__ ei, const float* __restrict__ ew,
                         unsigned long long* __restrict__ items, int* __restrict__ hist,
                         const float* __restrict__ wt, short* __restrict__ wtb) {
    __shared__ int lh[NBUCKET];
    __shared__ int nzf;
    int b = blockIdx.x;
    int tid = threadIdx.x;
    if (b < CVTBLK) {
        int t = b * 256 + tid;
        if (t >= NN * FF / 16) return;
        const float4* xp = (const float4*)x + t * 4;
        float4 v0 = xp[0], v1 = xp[1], v2 = xp[2], v3 = xp[3];
        float f[16] = {v0.x, v0.y, v0.z, v0.w, v1.x, v1.y, v1.z, v1.w,
                       v2.x, v2.y, v2.z, v2.w, v3.x, v3.y, v3.z, v3.w};
        unsigned short hs[16];
        #pragma unroll
        for (int j = 0; j < 16; ++j) {
            bf16 bb = (bf16)f[j];
            hs[j] = *(unsigned short*)&bb;
        }
        uint4* xbq = (uint4*)xb + t * 2;
        xbq[0] = ((uint4*)hs)[0];
        xbq[1] = ((uint4*)hs)[1];
        uint4 q;
        q.x = enc4(f[0], f[1], f[2], f[3]);
        q.y = enc4(f[4], f[5], f[6], f[7]);
        q.z = enc4(f[8], f[9], f[10], f[11]);
        q.w = enc4(f[12], f[13], f[14], f[15]);
        ((uint4*)xq)[t] = q;
    } else if (b < CVTBLK + NBE) {
        int bb = b - CVTBLK;
        if (tid == 0) nzf = 0;
        for (int j = tid; j < NBUCKET; j += 256) lh[j] = 0;
        __syncthreads();
        int eb = bb * ECHK;
        // layout detection on this chunk: int64 layout <=> all odd words zero
        unsigned acc = 0;
        for (int k = 0; k < ECHK / 256; ++k) {
            int e = eb + k * 256 + tid;
            if (e < EE) acc |= (unsigned)ei[2 * e + 1];
        }
        if (acc) nzf = 1;   // benign race, resolved by barrier
        __syncthreads();
        int flag = (nzf == 0) ? 1 : 0;
        for (int k = 0; k < ECHK / 256; ++k) {
            int e = eb + k * 256 + tid;
            if (e < EE) {
                int r, c; load_edge(ei, e, flag, r, c);
                unsigned key = (r == c) ? 0xFFFFu : (unsigned)r;
                items[e] = ((unsigned long long)((key << 16) | (unsigned)c) << 32)
                           | (unsigned long long)__float_as_uint(ew[e]);
                atomicAdd(&lh[min(key >> 7, (unsigned)NBKT_REAL)], 1);  // LDS
            }
        }
        __syncthreads();
        for (int j = tid; j < NBUCKET; j += 256) hist[j * NBE + bb] = lh[j];
    } else {
        int t = (b - CVTBLK - NBE) * 256 + tid;
        if (t >= 3 * FF * 168) return;
        int ph = t / (FF * 168);
        int rem = t - ph * FF * 168;
        int o = rem / 168;
        int i = rem - o * 168;
        short v = 0;
        if (i < FF) {
            // weight folding: out = x@(W0-W2) + T1@W1 + (L@T1)@(2*W2)
            float fv;
            if (ph == 0)      fv = wt[i * FF + o] - wt[2 * FF * FF + i * FF + o];
            else if (ph == 1) fv = wt[FF * FF + i * FF + o];
            else              fv = 2.0f * wt[2 * FF * FF + i * FF + o];
            bf16 bv = (bf16)fv;
            v = *(const short*)&bv;
        }
        wtb[t] = v;
    }
}

// ---------------- generic 2-level exclusive scan of hist[HM] (in place) ----------------
// After scanA1+scanA2: base(f) = hist[f] + bsumA[f>>8].

__global__ void scanA1_k(int* __restrict__ hist, int* __restrict__ bsumA) {
    __shared__ int wsum[4], woff[4];
    int b = blockIdx.x, tid = threadIdx.x;
    int wv = tid >> 6, ln = tid & 63;
    int i = b * 256 + tid;
    int v = (i < HM) ? hist[i] : 0;
    int xs = v;
    #pragma unroll
    for (int off = 1; off < 64; off <<= 1) {
        int t = __shfl_up(xs, off, 64);
        if (ln >= off) xs += t;
    }
    if (ln == 63) wsum[wv] = xs;
    __syncthreads();
    if (tid == 0) {
        int s = 0;
        #pragma unroll
        for (int j = 0; j < 4; ++j) { woff[j] = s; s += wsum[j]; }
        bsumA[b] = s;
    }
    __syncthreads();
    if (i < HM) hist[i] = woff[wv] + (xs - v);
}

__global__ void scanA2_k(int* __restrict__ bsumA) {
    __shared__ int wsum[4], woff[4];
    int tid = threadIdx.x, wv = tid >> 6, ln = tid & 63;
    int v = (tid < SCANBLK) ? bsumA[tid] : 0;
    int xs = v;
    #pragma unroll
    for (int off = 1; off < 64; off <<= 1) {
        int t = __shfl_up(xs, off, 64);
        if (ln >= off) xs += t;
    }
    if (ln == 63) wsum[wv] = xs;
    __syncthreads();
    if (tid == 0) {
        int s = 0;
        #pragma unroll
        for (int j = 0; j < 4; ++j) { woff[j] = s; s += wsum[j]; }
    }
    __syncthreads();
    if (tid < SCANBLK) bsumA[tid] = woff[wv] + (xs - v);
}

__device__ inline int hbase(const int* hist, const int* bsumA, int f) {
    return hist[f] + bsumA[f >> 8];
}

// ---------------- partition scatter: items -> sorted (grouped by bucket) ----------------
// lbase doubles as the fill counter (LDS returning atomics only). ECHK=8192 gives
// ~21 sequential 8B slots per bucket per block -> mostly full-line writes.

__global__ void pscat_k(const unsigned long long* __restrict__ items,
                        const int* __restrict__ hist, const int* __restrict__ bsumA,
                        unsigned long long* __restrict__ sorted) {
    __shared__ int lbase[NBUCKET];
    int b = blockIdx.x, tid = threadIdx.x;
    for (int j = tid; j < NBUCKET; j += 256) {
        int f = j * NBE + b;
        lbase[j] = hbase(hist, bsumA, f);
    }
    __syncthreads();
    int eb = b * ECHK;
    for (int k = 0; k < ECHK / 256; ++k) {
        int e = eb + k * 256 + tid;
        if (e < EE) {
            unsigned long long it = items[e];
            unsigned key = (unsigned)(it >> 48);
            int bk = (int)min(key >> 7, (unsigned)NBKT_REAL);
            int slot = atomicAdd(&lbase[bk], 1);   // LDS
            sorted[slot] = it;
        }
    }
}

// ---------------- fine1: per-bucket row histogram -> rowptr + dinv ----------------

__global__ void fine1_k(const unsigned long long* __restrict__ sorted,
                        const int* __restrict__ hist, const int* __restrict__ bsumA,
                        int* __restrict__ rowptr, float* __restrict__ dinv) {
    __shared__ int lh[128];
    __shared__ int wtot;
    int b = blockIdx.x, tid = threadIdx.x;
    if (tid < 128) lh[tid] = 0;
    int s = hbase(hist, bsumA, b * NBE);
    int e = hbase(hist, bsumA, (b + 1) * NBE);
    __syncthreads();
    for (int p = s + tid; p < e; p += 256)
        atomicAdd(&lh[(int)(unsigned)(sorted[p] >> 48) - b * 128], 1);  // LDS
    __syncthreads();
    int ln = tid & 63;
    int v = (tid < 128) ? lh[tid] : 0;
    int xs = v;
    #pragma unroll
    for (int off = 1; off < 64; off <<= 1) {
        int t = __shfl_up(xs, off, 64);
        if (ln >= off) xs += t;
    }
    if (tid == 63) wtot = xs;
    __syncthreads();
    int excl = xs - v + ((tid >= 64 && tid < 128) ? wtot : 0);
    int gr = b * 128 + tid;
    if (tid < 128 && gr < NN) {
        rowptr[gr] = s + excl;
        dinv[gr] = v > 0 ? rsqrtf((float)v) : 0.f;
    }
    if (b == NBKT_REAL - 1 && tid == 0) rowptr[NN] = e;  // end of real edges
}

// ---------------- fine2: write pairs in CSR order (coalesced region per bucket) ----------------

__global__ void fine2_k(const unsigned long long* __restrict__ sorted,
                        const int* __restrict__ hist, const int* __restrict__ bsumA,
                        const int* __restrict__ rowptr, const float* __restrict__ dinv,
                        unsigned* __restrict__ pairs) {
    __shared__ int lrp[128];
    __shared__ float ldv[128];
    int b = blockIdx.x, tid = threadIdx.x;
    int gr = b * 128 + tid;
    if (tid < 128) {
        lrp[tid] = (gr < NN) ? rowptr[gr] : 0;
        ldv[tid] = (gr < NN) ? dinv[gr] : 0.f;
    }
    int s = hbase(hist, bsumA, b * NBE);
    int e = hbase(hist, bsumA, (b + 1) * NBE);
    __syncthreads();
    for (int p = s + tid; p < e; p += 256) {
        unsigned long long it = sorted[p];
        int lr = (int)(unsigned)(it >> 48) - b * 128;
        unsigned c = (unsigned)(it >> 32) & 0xFFFFu;
        float w = __uint_as_float((unsigned)it);
        float lap = -ldv[lr] * dinv[c] * w;
        int slot = atomicAdd(&lrp[lr], 1);   // LDS
        bf16 lb = (bf16)lap;
        pairs[slot] = c | ((unsigned)*(unsigned short*)&lb << 16);
    }
}

// ---------------- SpMM fp8-gather: 9 threads/node, 16 fp8/edge, packed 4B edge stream ----------------
// WRITEQ=1: also emit fp8 of output (for next spmm). No x-correction pass needed
// anywhere (folded into weights).

template <int WRITEQ>
__global__ void spmm_k(const unsigned char* __restrict__ vq,
                       const int* __restrict__ rowptr, const unsigned* __restrict__ pairs,
                       bf16* __restrict__ y, unsigned char* __restrict__ yq) {
    int t = blockIdx.x * 256 + threadIdx.x;
    if (t >= NN * 9) return;
    int i = t / 9;
    int fo = (t - i * 9) * 16;
    const unsigned char* vp = vq + fo;

    float a[16];
    #pragma unroll
    for (int j = 0; j < 16; ++j) a[j] = 0.f;

    int s = rowptr[i], e = rowptr[i + 1];
    int p = s;
    for (; p + 1 < e; p += 2) {
        unsigned pr0 = pairs[p], pr1 = pairs[p + 1];
        uint4 u0 = *(const uint4*)(vp + (pr0 & 0xffffu) * FF);
        uint4 u1 = *(const uint4*)(vp + (pr1 & 0xffffu) * FF);
        fma16q(a, bhi(pr0), u0);
        fma16q(a, bhi(pr1), u1);
    }
    if (p < e) {
        unsigned pr = pairs[p];
        uint4 u = *(const uint4*)(vp + (pr & 0xffffu) * FF);
        fma16q(a, bhi(pr), u);
    }

    unsigned short hs[16];
    #pragma unroll
    for (int j = 0; j < 16; ++j) {
        bf16 b = (bf16)a[j];
        hs[j] = *(unsigned short*)&b;
    }
    uint4* yp = (uint4*)((unsigned short*)y + i * FF + fo);
    yp[0] = ((uint4*)hs)[0];
    yp[1] = ((uint4*)hs)[1];

    if (WRITEQ) {
        uint4 q;
        q.x = enc4(a[0], a[1], a[2], a[3]);
        q.y = enc4(a[4], a[5], a[6], a[7]);
        q.z = enc4(a[8], a[9], a[10], a[11]);
        q.w = enc4(a[12], a[13], a[14], a[15]);
        *(uint4*)(yq + i * FF + fo) = q;
    }
}

// ---------------- fused MFMA GEMM: full W resident in LDS, 1 block/CU, 16 waves ----------------

__global__ __launch_bounds__(1024)
void gemm_fused(const bf16* __restrict__ A0, const bf16* __restrict__ A1,
                const bf16* __restrict__ A2, const short* __restrict__ wtb,
                const float* __restrict__ bias, float* __restrict__ out) {
    __shared__ __align__(16) short Wt[3 * 144 * 168];   // 145,152 B
    int tid = threadIdx.x;

    {
        const uint4* Wg = (const uint4*)wtb;
        uint4* Wl = (uint4*)Wt;
        #pragma unroll
        for (int q = 0; q < 9; ++q) {
            int idx = q * 1024 + tid;
            if (idx < 9072) Wl[idx] = Wg[idx];
        }
    }
    __syncthreads();   // the ONLY barrier

    int wv = tid >> 6, ln = tid & 63;
    int m16 = ln & 15, quad = ln >> 4;
    int tile = wv * 256 + blockIdx.x;
    if (tile * 16 >= NN) return;
    int rowBase = tile * 16;
    int row = rowBase + m16;

    const bf16* const srcs[3] = {A0, A1, A2};
    const short8 zero8 = {0, 0, 0, 0, 0, 0, 0, 0};

    floatx4 acc[9];
    #pragma unroll
    for (int q = 0; q < 9; ++q) acc[q] = (floatx4){0.f, 0.f, 0.f, 0.f};

    #pragma unroll
    for (int ph = 0; ph < 3; ++ph) {
        const bf16* A = srcs[ph];
        short8 a[5];
        #pragma unroll
        for (int kt = 0; kt < 5; ++kt) {
            int k0 = kt * 32 + quad * 8;
            if (k0 < FF)
                a[kt] = *(const short8*)((const short*)A + row * FF + k0);
            else
                a[kt] = zero8;
        }

        const short* Wp = Wt + ph * 144 * 168;
        #pragma unroll
        for (int nt = 0; nt < 9; ++nt) {
            #pragma unroll
            for (int kt = 0; kt < 5; ++kt) {
                short8 b = *(const short8*)&Wp[(nt * 16 + m16) * 168 + kt * 32 + quad * 8];
                acc[nt] = __builtin_amdgcn_mfma_f32_16x16x32_bf16(a[kt], b, acc[nt], 0, 0, 0);
            }
        }
    }

    int rowc = rowBase + quad * 4;
    #pragma unroll
    for (int nt = 0; nt < 9; ++nt) {
        int col = nt * 16 + m16;
        float bs = bias[col];
        #pragma unroll
        for (int r = 0; r < 4; ++r) {
            int rr = rowc + r;
            out[rr * FF + col] = acc[nt][r] + bs;
        }
    }
}

// ---------------- launch ----------------

extern "C" void kernel_launch(void* const* d_in, const int* in_sizes, int n_in,
                              void* d_out, int out_size, void* d_ws, size_t ws_size,
                              hipStream_t stream) {
    int ix = -1, iei = -1, iew = -1, iwt = -1, ib = -1;
    for (int i = 0; i < n_in; ++i) {
        switch (in_sizes[i]) {
            case NN * FF:      if (ix  < 0) ix  = i; break;
            case 2 * EE:       if (iei < 0) iei = i; break;
            case EE:           if (iew < 0) iew = i; break;
            case 3 * FF * FF:  if (iwt < 0) iwt = i; break;
            case FF:           if (ib  < 0) ib  = i; break;
        }
    }
    if (ix < 0 || iei < 0 || iew < 0 || iwt < 0 || ib < 0) {
        ix = 0; iei = 1; iew = 2; iwt = 3; ib = 4;
    }
    const float* x    = (const float*)d_in[ix];
    const int*   ei   = (const int*)d_in[iei];
    const float* ew   = (const float*)d_in[iew];
    const float* wt   = (const float*)d_in[iwt];
    const float* bias = (const float*)d_in[ib];
    float* out = (float*)d_out;

    // Workspace layout (75.3 MB, all offsets 16B-aligned):
    char* p = (char*)d_ws;
    unsigned long long* items  = (unsigned long long*)(p + 0);          // 6.4 MB
    unsigned long long* sorted = (unsigned long long*)(p + 6400000);    // 6.4 MB
    int*      hist   = (int*)(p + 12800000);             // HM ints = 154 KB
    int*      bsumA  = (int*)(p + 13500000);             // SCANBLK ints
    int*      rowptr = (int*)(p + 13600000);             // N+1 ints
    float*    dinv   = (float*)(p + 13900000);           // N floats
    unsigned* pairs  = (unsigned*)(p + 14200000);        // E words = 3.2 MB
    short*    wtb    = (short*)(p + 17500000);           // 145,152 B
    bf16*     tx1    = (bf16*)(p + 17700000);            // 14.4 MB
    bf16*     tx2    = (bf16*)(p + 32100000);            // 14.4 MB
    unsigned char* xq   = (unsigned char*)(p + 46500000); // 7.2 MB
    unsigned char* tx1q = (unsigned char*)(p + 53700000); // 7.2 MB
    bf16*     xb     = (bf16*)(p + 60900000);            // 14.4 MB -> ends 75,300,000

    if (ws_size < 75300000) return;

    int spGrid = (NN * 9 + 255) / 256;

    fusedA_k<<<CVTBLK + NBE + WGRID, 256, 0, stream>>>(x, xb, xq, ei, ew, items, hist,
                                                       wt, wtb);
    scanA1_k<<<SCANBLK, 256, 0, stream>>>(hist, bsumA);
    scanA2_k<<<1, 256, 0, stream>>>(bsumA);
    pscat_k<<<NBE, 256, 0, stream>>>(items, hist, bsumA, sorted);
    fine1_k<<<NBKT_REAL, 256, 0, stream>>>(sorted, hist, bsumA, rowptr, dinv);
    fine2_k<<<NBKT_REAL, 256, 0, stream>>>(sorted, hist, bsumA, rowptr, dinv, pairs);

    spmm_k<1><<<spGrid, 256, 0, stream>>>(xq, rowptr, pairs, tx1, tx1q);
    spmm_k<0><<<spGrid, 256, 0, stream>>>(tx1q, rowptr, pairs, tx2, (unsigned char*)0);
    gemm_fused<<<256, 1024, 0, stream>>>(xb, tx1, tx2, wtb, bias, out);
}

// Round 6
// 190.282 us; speedup vs baseline: 1.0757x; 1.0757x over previous
//
#include <hip/hip_runtime.h>
#include <hip/hip_bf16.h>

#define NN 50000
#define EE 800000
#define FF 144
#define CVTBLK 1758      // ceil(NN*FF/16/256)
#define ECHK 2048        // edges per partition block (391 blocks: occupancy > write locality)
#define NBE 391          // ceil(EE/ECHK)
#define NBKT_REAL 391    // row buckets of 128 rows (covers 50048)
#define NBUCKET 392      // + 1 self-loop bucket
#define WGRID 284        // ceil(3*144*168/256)
#define HM (NBUCKET * NBE)   // 153272 histogram entries
#define SCANBLK 599      // ceil(HM/256)

typedef __hip_bfloat16 bf16;
typedef __attribute__((ext_vector_type(8))) short short8;
typedef __attribute__((ext_vector_type(4))) float floatx4;
typedef __attribute__((ext_vector_type(2))) float float2v;

__device__ inline float blo(unsigned x) { return __uint_as_float(x << 16); }
__device__ inline float bhi(unsigned x) { return __uint_as_float(x & 0xffff0000u); }

// ---- fp8 e4m3 pack/unpack (gfx950 OCP) ----
__device__ inline void dec4fma(float* a, float l, unsigned d) {
    float2v p0 = __builtin_amdgcn_cvt_pk_f32_fp8((int)d, false);
    float2v p1 = __builtin_amdgcn_cvt_pk_f32_fp8((int)d, true);
    a[0] = fmaf(l, p0.x, a[0]);
    a[1] = fmaf(l, p0.y, a[1]);
    a[2] = fmaf(l, p1.x, a[2]);
    a[3] = fmaf(l, p1.y, a[3]);
}
__device__ inline void fma16q(float* a, float l, uint4 u) {
    dec4fma(a + 0, l, u.x);
    dec4fma(a + 4, l, u.y);
    dec4fma(a + 8, l, u.z);
    dec4fma(a + 12, l, u.w);
}
__device__ inline unsigned enc4(float a, float b, float c, float d) {
    int w = __builtin_amdgcn_cvt_pk_fp8_f32(a, b, 0, false);
    w = __builtin_amdgcn_cvt_pk_fp8_f32(c, d, w, true);
    return (unsigned)w;
}

__device__ inline void load_edge(const int* ei, int e, int flag, int& r, int& c) {
    if (flag) { r = ei[2 * e]; c = ei[2 * EE + 2 * e]; }
    else      { r = ei[e];     c = ei[EE + e]; }
}

// ---------------- fused A: cvt(x) | detect+pack+bucket-hist(edges) | cvt+fold(W) ----------------
// Blocks [0,CVTBLK): x fp32 -> bf16 + fp8.
// Blocks [CVTBLK, +NBE): self-detect edge_index layout on own chunk (OR of odd words),
//   pack edges into u64 items {row:16|col:16|w_fp32:32}, LDS histogram over 392
//   row-buckets (bucket = row>>7; self-loops -> 391). ZERO global atomics.
// Blocks [CVTBLK+NBE, +WGRID): W fp32 -> bf16 FOLDED (W0-W2, W1, 2*W2), transposed
//   padded wtb[ph][o][i].

__global__ void fusedA_k(const float* __restrict__ x, bf16* __restrict__ xb,
                         unsigned char* __restrict__ xq,
                         const int* __restrict__ ei, const float* __restrict__ ew,
                         unsigned long long* __restrict__ items, int* __restrict__ hist,
                         const float* __restrict__ wt, short* __restrict__ wtb) {
    __shared__ int lh[NBUCKET];
    __shared__ int nzf;
    int b = blockIdx.x;
    int tid = threadIdx.x;
    if (b < CVTBLK) {
        int t = b * 256 + tid;
        if (t >= NN * FF / 16) return;
        const float4* xp = (const float4*)x + t * 4;
        float4 v0 = xp[0], v1 = xp[1], v2 = xp[2], v3 = xp[3];
        float f[16] = {v0.x, v0.y, v0.z, v0.w, v1.x, v1.y, v1.z, v1.w,
                       v2.x, v2.y, v2.z, v2.w, v3.x, v3.y, v3.z, v3.w};
        unsigned short hs[16];
        #pragma unroll
        for (int j = 0; j < 16; ++j) {
            bf16 bb = (bf16)f[j];
            hs[j] = *(unsigned short*)&bb;
        }
        uint4* xbq = (uint4*)xb + t * 2;
        xbq[0] = ((uint4*)hs)[0];
        xbq[1] = ((uint4*)hs)[1];
        uint4 q;
        q.x = enc4(f[0], f[1], f[2], f[3]);
        q.y = enc4(f[4], f[5], f[6], f[7]);
        q.z = enc4(f[8], f[9], f[10], f[11]);
        q.w = enc4(f[12], f[13], f[14], f[15]);
        ((uint4*)xq)[t] = q;
    } else if (b < CVTBLK + NBE) {
        int bb = b - CVTBLK;
        if (tid == 0) nzf = 0;
        for (int j = tid; j < NBUCKET; j += 256) lh[j] = 0;
        __syncthreads();
        int eb = bb * ECHK;
        // layout detection on this chunk: int64 layout <=> all odd words zero
        unsigned acc = 0;
        #pragma unroll
        for (int k = 0; k < ECHK / 256; ++k) {
            int e = eb + k * 256 + tid;
            if (e < EE) acc |= (unsigned)ei[2 * e + 1];
        }
        if (acc) nzf = 1;   // benign race, resolved by barrier
        __syncthreads();
        int flag = (nzf == 0) ? 1 : 0;
        #pragma unroll
        for (int k = 0; k < ECHK / 256; ++k) {
            int e = eb + k * 256 + tid;
            if (e < EE) {
                int r, c; load_edge(ei, e, flag, r, c);
                unsigned key = (r == c) ? 0xFFFFu : (unsigned)r;
                items[e] = ((unsigned long long)((key << 16) | (unsigned)c) << 32)
                           | (unsigned long long)__float_as_uint(ew[e]);
                atomicAdd(&lh[min(key >> 7, (unsigned)NBKT_REAL)], 1);  // LDS
            }
        }
        __syncthreads();
        for (int j = tid; j < NBUCKET; j += 256) hist[j * NBE + bb] = lh[j];
    } else {
        int t = (b - CVTBLK - NBE) * 256 + tid;
        if (t >= 3 * FF * 168) return;
        int ph = t / (FF * 168);
        int rem = t - ph * FF * 168;
        int o = rem / 168;
        int i = rem - o * 168;
        short v = 0;
        if (i < FF) {
            // weight folding: out = x@(W0-W2) + T1@W1 + (L@T1)@(2*W2)
            float fv;
            if (ph == 0)      fv = wt[i * FF + o] - wt[2 * FF * FF + i * FF + o];
            else if (ph == 1) fv = wt[FF * FF + i * FF + o];
            else              fv = 2.0f * wt[2 * FF * FF + i * FF + o];
            bf16 bv = (bf16)fv;
            v = *(const short*)&bv;
        }
        wtb[t] = v;
    }
}

// ---------------- generic 2-level exclusive scan of hist[HM] (in place) ----------------
// After scanA1+scanA2: base(f) = hist[f] + bsumA[f>>8].

__global__ void scanA1_k(int* __restrict__ hist, int* __restrict__ bsumA) {
    __shared__ int wsum[4], woff[4];
    int b = blockIdx.x, tid = threadIdx.x;
    int wv = tid >> 6, ln = tid & 63;
    int i = b * 256 + tid;
    int v = (i < HM) ? hist[i] : 0;
    int xs = v;
    #pragma unroll
    for (int off = 1; off < 64; off <<= 1) {
        int t = __shfl_up(xs, off, 64);
        if (ln >= off) xs += t;
    }
    if (ln == 63) wsum[wv] = xs;
    __syncthreads();
    if (tid == 0) {
        int s = 0;
        #pragma unroll
        for (int j = 0; j < 4; ++j) { woff[j] = s; s += wsum[j]; }
        bsumA[b] = s;
    }
    __syncthreads();
    if (i < HM) hist[i] = woff[wv] + (xs - v);
}

__global__ __launch_bounds__(1024) void scanA2_k(int* __restrict__ bsumA) {
    __shared__ int wsum[16], woff[16];
    int tid = threadIdx.x, wv = tid >> 6, ln = tid & 63;
    int v = (tid < SCANBLK) ? bsumA[tid] : 0;
    int xs = v;
    #pragma unroll
    for (int off = 1; off < 64; off <<= 1) {
        int t = __shfl_up(xs, off, 64);
        if (ln >= off) xs += t;
    }
    if (ln == 63) wsum[wv] = xs;
    __syncthreads();
    if (tid == 0) {
        int s = 0;
        #pragma unroll
        for (int j = 0; j < 16; ++j) { woff[j] = s; s += wsum[j]; }
    }
    __syncthreads();
    if (tid < SCANBLK) bsumA[tid] = woff[wv] + (xs - v);
}

__device__ inline int hbase(const int* hist, const int* bsumA, int f) {
    return hist[f] + bsumA[f >> 8];
}

// ---------------- partition scatter: items -> sorted (grouped by bucket) ----------------
// lbase doubles as the fill counter (LDS returning atomics only).

__global__ void pscat_k(const unsigned long long* __restrict__ items,
                        const int* __restrict__ hist, const int* __restrict__ bsumA,
                        unsigned long long* __restrict__ sorted) {
    __shared__ int lbase[NBUCKET];
    int b = blockIdx.x, tid = threadIdx.x;
    for (int j = tid; j < NBUCKET; j += 256) {
        int f = j * NBE + b;
        lbase[j] = hbase(hist, bsumA, f);
    }
    __syncthreads();
    int eb = b * ECHK;
    #pragma unroll
    for (int k = 0; k < ECHK / 256; ++k) {
        int e = eb + k * 256 + tid;
        if (e < EE) {
            unsigned long long it = items[e];
            unsigned key = (unsigned)(it >> 48);
            int bk = (int)min(key >> 7, (unsigned)NBKT_REAL);
            int slot = atomicAdd(&lbase[bk], 1);   // LDS
            sorted[slot] = it;
        }
    }
}

// ---------------- fine1: per-bucket row histogram -> rowptr + dinv ----------------

__global__ void fine1_k(const unsigned long long* __restrict__ sorted,
                        const int* __restrict__ hist, const int* __restrict__ bsumA,
                        int* __restrict__ rowptr, float* __restrict__ dinv) {
    __shared__ int lh[128];
    __shared__ int wtot;
    int b = blockIdx.x, tid = threadIdx.x;
    if (tid < 128) lh[tid] = 0;
    int s = hbase(hist, bsumA, b * NBE);
    int e = hbase(hist, bsumA, (b + 1) * NBE);
    __syncthreads();
    for (int p = s + tid; p < e; p += 256)
        atomicAdd(&lh[(int)(unsigned)(sorted[p] >> 48) - b * 128], 1);  // LDS
    __syncthreads();
    int ln = tid & 63;
    int v = (tid < 128) ? lh[tid] : 0;
    int xs = v;
    #pragma unroll
    for (int off = 1; off < 64; off <<= 1) {
        int t = __shfl_up(xs, off, 64);
        if (ln >= off) xs += t;
    }
    if (tid == 63) wtot = xs;
    __syncthreads();
    int excl = xs - v + ((tid >= 64 && tid < 128) ? wtot : 0);
    int gr = b * 128 + tid;
    if (tid < 128 && gr < NN) {
        rowptr[gr] = s + excl;
        dinv[gr] = v > 0 ? rsqrtf((float)v) : 0.f;
    }
    if (b == NBKT_REAL - 1 && tid == 0) rowptr[NN] = e;  // end of real edges
}

// ---------------- fine2: write pairs in CSR order (coalesced region per bucket) ----------------

__global__ void fine2_k(const unsigned long long* __restrict__ sorted,
                        const int* __restrict__ hist, const int* __restrict__ bsumA,
                        const int* __restrict__ rowptr, const float* __restrict__ dinv,
                        unsigned* __restrict__ pairs) {
    __shared__ int lrp[128];
    __shared__ float ldv[128];
    int b = blockIdx.x, tid = threadIdx.x;
    int gr = b * 128 + tid;
    if (tid < 128) {
        lrp[tid] = (gr < NN) ? rowptr[gr] : 0;
        ldv[tid] = (gr < NN) ? dinv[gr] : 0.f;
    }
    int s = hbase(hist, bsumA, b * NBE);
    int e = hbase(hist, bsumA, (b + 1) * NBE);
    __syncthreads();
    for (int p = s + tid; p < e; p += 256) {
        unsigned long long it = sorted[p];
        int lr = (int)(unsigned)(it >> 48) - b * 128;
        unsigned c = (unsigned)(it >> 32) & 0xFFFFu;
        float w = __uint_as_float((unsigned)it);
        float lap = -ldv[lr] * dinv[c] * w;
        int slot = atomicAdd(&lrp[lr], 1);   // LDS
        bf16 lb = (bf16)lap;
        pairs[slot] = c | ((unsigned)*(unsigned short*)&lb << 16);
    }
}

// ---------------- SpMM fp8-gather: 9 threads/node, 16 fp8/edge, packed 4B edge stream ----------------
// WRITEQ=1: also emit fp8 of output (for next spmm). No x-correction pass needed
// anywhere (folded into weights).

template <int WRITEQ>
__global__ void spmm_k(const unsigned char* __restrict__ vq,
                       const int* __restrict__ rowptr, const unsigned* __restrict__ pairs,
                       bf16* __restrict__ y, unsigned char* __restrict__ yq) {
    int t = blockIdx.x * 256 + threadIdx.x;
    if (t >= NN * 9) return;
    int i = t / 9;
    int fo = (t - i * 9) * 16;
    const unsigned char* vp = vq + fo;

    float a[16];
    #pragma unroll
    for (int j = 0; j < 16; ++j) a[j] = 0.f;

    int s = rowptr[i], e = rowptr[i + 1];
    int p = s;
    for (; p + 1 < e; p += 2) {
        unsigned pr0 = pairs[p], pr1 = pairs[p + 1];
        uint4 u0 = *(const uint4*)(vp + (pr0 & 0xffffu) * FF);
        uint4 u1 = *(const uint4*)(vp + (pr1 & 0xffffu) * FF);
        fma16q(a, bhi(pr0), u0);
        fma16q(a, bhi(pr1), u1);
    }
    if (p < e) {
        unsigned pr = pairs[p];
        uint4 u = *(const uint4*)(vp + (pr & 0xffffu) * FF);
        fma16q(a, bhi(pr), u);
    }

    unsigned short hs[16];
    #pragma unroll
    for (int j = 0; j < 16; ++j) {
        bf16 b = (bf16)a[j];
        hs[j] = *(unsigned short*)&b;
    }
    uint4* yp = (uint4*)((unsigned short*)y + i * FF + fo);
    yp[0] = ((uint4*)hs)[0];
    yp[1] = ((uint4*)hs)[1];

    if (WRITEQ) {
        uint4 q;
        q.x = enc4(a[0], a[1], a[2], a[3]);
        q.y = enc4(a[4], a[5], a[6], a[7]);
        q.z = enc4(a[8], a[9], a[10], a[11]);
        q.w = enc4(a[12], a[13], a[14], a[15]);
        *(uint4*)(yq + i * FF + fo) = q;
    }
}

// ---------------- fused MFMA GEMM: full W resident in LDS, 1 block/CU, 16 waves ----------------

__global__ __launch_bounds__(1024)
void gemm_fused(const bf16* __restrict__ A0, const bf16* __restrict__ A1,
                const bf16* __restrict__ A2, const short* __restrict__ wtb,
                const float* __restrict__ bias, float* __restrict__ out) {
    __shared__ __align__(16) short Wt[3 * 144 * 168];   // 145,152 B
    int tid = threadIdx.x;

    {
        const uint4* Wg = (const uint4*)wtb;
        uint4* Wl = (uint4*)Wt;
        #pragma unroll
        for (int q = 0; q < 9; ++q) {
            int idx = q * 1024 + tid;
            if (idx < 9072) Wl[idx] = Wg[idx];
        }
    }
    __syncthreads();   // the ONLY barrier

    int wv = tid >> 6, ln = tid & 63;
    int m16 = ln & 15, quad = ln >> 4;
    int tile = wv * 256 + blockIdx.x;
    if (tile * 16 >= NN) return;
    int rowBase = tile * 16;
    int row = rowBase + m16;

    const bf16* const srcs[3] = {A0, A1, A2};
    const short8 zero8 = {0, 0, 0, 0, 0, 0, 0, 0};

    floatx4 acc[9];
    #pragma unroll
    for (int q = 0; q < 9; ++q) acc[q] = (floatx4){0.f, 0.f, 0.f, 0.f};

    #pragma unroll
    for (int ph = 0; ph < 3; ++ph) {
        const bf16* A = srcs[ph];
        short8 a[5];
        #pragma unroll
        for (int kt = 0; kt < 5; ++kt) {
            int k0 = kt * 32 + quad * 8;
            if (k0 < FF)
                a[kt] = *(const short8*)((const short*)A + row * FF + k0);
            else
                a[kt] = zero8;
        }

        const short* Wp = Wt + ph * 144 * 168;
        #pragma unroll
        for (int nt = 0; nt < 9; ++nt) {
            #pragma unroll
            for (int kt = 0; kt < 5; ++kt) {
                short8 b = *(const short8*)&Wp[(nt * 16 + m16) * 168 + kt * 32 + quad * 8];
                acc[nt] = __builtin_amdgcn_mfma_f32_16x16x32_bf16(a[kt], b, acc[nt], 0, 0, 0);
            }
        }
    }

    int rowc = rowBase + quad * 4;
    #pragma unroll
    for (int nt = 0; nt < 9; ++nt) {
        int col = nt * 16 + m16;
        float bs = bias[col];
        #pragma unroll
        for (int r = 0; r < 4; ++r) {
            int rr = rowc + r;
            out[rr * FF + col] = acc[nt][r] + bs;
        }
    }
}

// ---------------- launch ----------------

extern "C" void kernel_launch(void* const* d_in, const int* in_sizes, int n_in,
                              void* d_out, int out_size, void* d_ws, size_t ws_size,
                              hipStream_t stream) {
    int ix = -1, iei = -1, iew = -1, iwt = -1, ib = -1;
    for (int i = 0; i < n_in; ++i) {
        switch (in_sizes[i]) {
            case NN * FF:      if (ix  < 0) ix  = i; break;
            case 2 * EE:       if (iei < 0) iei = i; break;
            case EE:           if (iew < 0) iew = i; break;
            case 3 * FF * FF:  if (iwt < 0) iwt = i; break;
            case FF:           if (ib  < 0) ib  = i; break;
        }
    }
    if (ix < 0 || iei < 0 || iew < 0 || iwt < 0 || ib < 0) {
        ix = 0; iei = 1; iew = 2; iwt = 3; ib = 4;
    }
    const float* x    = (const float*)d_in[ix];
    const int*   ei   = (const int*)d_in[iei];
    const float* ew   = (const float*)d_in[iew];
    const float* wt   = (const float*)d_in[iwt];
    const float* bias = (const float*)d_in[ib];
    float* out = (float*)d_out;

    // Workspace layout (75.3 MB, all offsets 16B-aligned):
    char* p = (char*)d_ws;
    unsigned long long* items  = (unsigned long long*)(p + 0);          // 6.4 MB
    unsigned long long* sorted = (unsigned long long*)(p + 6400000);    // 6.4 MB
    int*      hist   = (int*)(p + 12800000);             // HM ints = 613 KB
    int*      bsumA  = (int*)(p + 13500000);             // SCANBLK ints
    int*      rowptr = (int*)(p + 13600000);             // N+1 ints
    float*    dinv   = (float*)(p + 13900000);           // N floats
    unsigned* pairs  = (unsigned*)(p + 14200000);        // E words = 3.2 MB
    short*    wtb    = (short*)(p + 17500000);           // 145,152 B
    bf16*     tx1    = (bf16*)(p + 17700000);            // 14.4 MB
    bf16*     tx2    = (bf16*)(p + 32100000);            // 14.4 MB
    unsigned char* xq   = (unsigned char*)(p + 46500000); // 7.2 MB
    unsigned char* tx1q = (unsigned char*)(p + 53700000); // 7.2 MB
    bf16*     xb     = (bf16*)(p + 60900000);            // 14.4 MB -> ends 75,300,000

    if (ws_size < 75300000) return;

    int spGrid = (NN * 9 + 255) / 256;

    fusedA_k<<<CVTBLK + NBE + WGRID, 256, 0, stream>>>(x, xb, xq, ei, ew, items, hist,
                                                       wt, wtb);
    scanA1_k<<<SCANBLK, 256, 0, stream>>>(hist, bsumA);
    scanA2_k<<<1, 1024, 0, stream>>>(bsumA);
    pscat_k<<<NBE, 256, 0, stream>>>(items, hist, bsumA, sorted);
    fine1_k<<<NBKT_REAL, 256, 0, stream>>>(sorted, hist, bsumA, rowptr, dinv);
    fine2_k<<<NBKT_REAL, 256, 0, stream>>>(sorted, hist, bsumA, rowptr, dinv, pairs);

    spmm_k<1><<<spGrid, 256, 0, stream>>>(xq, rowptr, pairs, tx1, tx1q);
    spmm_k<0><<<spGrid, 256, 0, stream>>>(tx1q, rowptr, pairs, tx2, (unsigned char*)0);
    gemm_fused<<<256, 1024, 0, stream>>>(xb, tx1, tx2, wtb, bias, out);
}

// Round 7
// 186.781 us; speedup vs baseline: 1.0959x; 1.0187x over previous
//
#include <hip/hip_runtime.h>
#include <hip/hip_bf16.h>
#include <hip/hip_cooperative_groups.h>

namespace cg = cooperative_groups;

#define NN 50000
#define EE 800000
#define FF 144
#define CVTBLK 1758      // ceil(NN*FF/16/256)
#define ECHK 2048        // edges per partition block
#define NBE 391          // ceil(EE/ECHK)
#define NBKT_REAL 391    // row buckets of 128 rows
#define NBUCKET 392      // + self-loop bucket
#define WGRID 284        // ceil(3*FF*168/256)
#define HM (NBUCKET * NBE)
#define SCANBLK 599      // ceil(HM/256)
#define SPBLK 1758       // ceil(NN*9/256)
#define NV0 (CVTBLK + NBE + WGRID)   // 2433 virtual blocks in phase 0
#define MGRID 1536       // 6 blocks/CU on 256 CUs (cooperative co-residency)

typedef __hip_bfloat16 bf16;
typedef __attribute__((ext_vector_type(8))) short short8;
typedef __attribute__((ext_vector_type(4))) float floatx4;
typedef __attribute__((ext_vector_type(2))) float float2v;

__device__ inline float blo(unsigned x) { return __uint_as_float(x << 16); }
__device__ inline float bhi(unsigned x) { return __uint_as_float(x & 0xffff0000u); }

// ---- fp8 e4m3 pack/unpack (gfx950 OCP) ----
__device__ inline void dec4fma(float* a, float l, unsigned d) {
    float2v p0 = __builtin_amdgcn_cvt_pk_f32_fp8((int)d, false);
    float2v p1 = __builtin_amdgcn_cvt_pk_f32_fp8((int)d, true);
    a[0] = fmaf(l, p0.x, a[0]);
    a[1] = fmaf(l, p0.y, a[1]);
    a[2] = fmaf(l, p1.x, a[2]);
    a[3] = fmaf(l, p1.y, a[3]);
}
__device__ inline void fma16q(float* a, float l, uint4 u) {
    dec4fma(a + 0, l, u.x);
    dec4fma(a + 4, l, u.y);
    dec4fma(a + 8, l, u.z);
    dec4fma(a + 12, l, u.w);
}
__device__ inline unsigned enc4(float a, float b, float c, float d) {
    int w = __builtin_amdgcn_cvt_pk_fp8_f32(a, b, 0, false);
    w = __builtin_amdgcn_cvt_pk_fp8_f32(c, d, w, true);
    return (unsigned)w;
}

__device__ inline void load_edge(const int* ei, int e, int flag, int& r, int& c) {
    if (flag) { r = ei[2 * e]; c = ei[2 * EE + 2 * e]; }
    else      { r = ei[e];     c = ei[EE + e]; }
}

// ================= device phase bodies (shared by mega + fallback kernels) =================

__device__ inline void dev_cvt(int b, int tid, const float* __restrict__ x,
                               bf16* __restrict__ xb, unsigned char* __restrict__ xq) {
    int t = b * 256 + tid;
    if (t >= NN * FF / 16) return;           // no barriers inside: early return is safe
    const float4* xp = (const float4*)x + t * 4;
    float4 v0 = xp[0], v1 = xp[1], v2 = xp[2], v3 = xp[3];
    float f[16] = {v0.x, v0.y, v0.z, v0.w, v1.x, v1.y, v1.z, v1.w,
                   v2.x, v2.y, v2.z, v2.w, v3.x, v3.y, v3.z, v3.w};
    unsigned short hs[16];
    #pragma unroll
    for (int j = 0; j < 16; ++j) {
        bf16 bb = (bf16)f[j];
        hs[j] = *(unsigned short*)&bb;
    }
    uint4* xbq = (uint4*)xb + t * 2;
    xbq[0] = ((uint4*)hs)[0];
    xbq[1] = ((uint4*)hs)[1];
    uint4 q;
    q.x = enc4(f[0], f[1], f[2], f[3]);
    q.y = enc4(f[4], f[5], f[6], f[7]);
    q.z = enc4(f[8], f[9], f[10], f[11]);
    q.w = enc4(f[12], f[13], f[14], f[15]);
    ((uint4*)xq)[t] = q;
}

__device__ inline void dev_edge(int bb, int tid, const int* __restrict__ ei,
                                const float* __restrict__ ew,
                                unsigned long long* __restrict__ items,
                                int* __restrict__ hist, int* lh, int* nzf) {
    if (tid == 0) *nzf = 0;
    for (int j = tid; j < NBUCKET; j += 256) lh[j] = 0;
    __syncthreads();
    int eb = bb * ECHK;
    unsigned acc = 0;
    #pragma unroll
    for (int k = 0; k < ECHK / 256; ++k) {
        int e = eb + k * 256 + tid;
        if (e < EE) acc |= (unsigned)ei[2 * e + 1];
    }
    if (acc) *nzf = 1;   // benign race, resolved by barrier
    __syncthreads();
    int flag = (*nzf == 0) ? 1 : 0;
    #pragma unroll
    for (int k = 0; k < ECHK / 256; ++k) {
        int e = eb + k * 256 + tid;
        if (e < EE) {
            int r, c; load_edge(ei, e, flag, r, c);
            unsigned key = (r == c) ? 0xFFFFu : (unsigned)r;
            items[e] = ((unsigned long long)((key << 16) | (unsigned)c) << 32)
                       | (unsigned long long)__float_as_uint(ew[e]);
            atomicAdd(&lh[min(key >> 7, (unsigned)NBKT_REAL)], 1);  // LDS
        }
    }
    __syncthreads();
    for (int j = tid; j < NBUCKET; j += 256) hist[j * NBE + bb] = lh[j];
}

__device__ inline void dev_cvtw(int b, int tid, const float* __restrict__ wt,
                                short* __restrict__ wtb) {
    int t = b * 256 + tid;
    if (t >= 3 * FF * 168) return;
    int ph = t / (FF * 168);
    int rem = t - ph * FF * 168;
    int o = rem / 168;
    int i = rem - o * 168;
    short v = 0;
    if (i < FF) {
        // weight folding: out = x@(W0-W2) + T1@W1 + (L@T1)@(2*W2)
        float fv;
        if (ph == 0)      fv = wt[i * FF + o] - wt[2 * FF * FF + i * FF + o];
        else if (ph == 1) fv = wt[FF * FF + i * FF + o];
        else              fv = 2.0f * wt[2 * FF * FF + i * FF + o];
        bf16 bv = (bf16)fv;
        v = *(const short*)&bv;
    }
    wtb[t] = v;
}

__device__ inline void dev_scanA1(int b, int tid, int* __restrict__ hist,
                                  int* __restrict__ bsumA, int* wsum, int* woff) {
    int wv = tid >> 6, ln = tid & 63;
    int i = b * 256 + tid;
    int v = (i < HM) ? hist[i] : 0;
    int xs = v;
    #pragma unroll
    for (int off = 1; off < 64; off <<= 1) {
        int t = __shfl_up(xs, off, 64);
        if (ln >= off) xs += t;
    }
    if (ln == 63) wsum[wv] = xs;
    __syncthreads();
    if (tid == 0) {
        int s = 0;
        #pragma unroll
        for (int j = 0; j < 4; ++j) { woff[j] = s; s += wsum[j]; }
        bsumA[b] = s;
    }
    __syncthreads();
    if (i < HM) hist[i] = woff[wv] + (xs - v);
}

// 256-thread scan of bsumA[SCANBLK] (3 entries/thread; 768 >= 599)
__device__ inline void dev_scanA2(int tid, int* __restrict__ bsumA, int* wsum, int* woff) {
    int wv = tid >> 6, ln = tid & 63;
    int j0 = tid * 3;
    int v0 = (j0 < SCANBLK) ? bsumA[j0] : 0;
    int v1 = (j0 + 1 < SCANBLK) ? bsumA[j0 + 1] : 0;
    int v2 = (j0 + 2 < SCANBLK) ? bsumA[j0 + 2] : 0;
    int sv = v0 + v1 + v2;
    int xs = sv;
    #pragma unroll
    for (int off = 1; off < 64; off <<= 1) {
        int t = __shfl_up(xs, off, 64);
        if (ln >= off) xs += t;
    }
    if (ln == 63) wsum[wv] = xs;
    __syncthreads();
    if (tid == 0) {
        int s = 0;
        #pragma unroll
        for (int j = 0; j < 4; ++j) { woff[j] = s; s += wsum[j]; }
    }
    __syncthreads();
    int o = woff[wv] + (xs - sv);
    if (j0 < SCANBLK) bsumA[j0] = o;
    if (j0 + 1 < SCANBLK) bsumA[j0 + 1] = o + v0;
    if (j0 + 2 < SCANBLK) bsumA[j0 + 2] = o + v0 + v1;
}

__device__ inline int hbase(const int* hist, const int* bsumA, int f) {
    return hist[f] + bsumA[f >> 8];
}

__device__ inline void dev_pscat(int b, int tid, const unsigned long long* __restrict__ items,
                                 const int* __restrict__ hist, const int* __restrict__ bsumA,
                                 unsigned long long* __restrict__ sorted, int* lbase) {
    for (int j = tid; j < NBUCKET; j += 256) lbase[j] = hbase(hist, bsumA, j * NBE + b);
    __syncthreads();
    int eb = b * ECHK;
    #pragma unroll
    for (int k = 0; k < ECHK / 256; ++k) {
        int e = eb + k * 256 + tid;
        if (e < EE) {
            unsigned long long it = items[e];
            unsigned key = (unsigned)(it >> 48);
            int bk = (int)min(key >> 7, (unsigned)NBKT_REAL);
            int slot = atomicAdd(&lbase[bk], 1);   // LDS
            sorted[slot] = it;
        }
    }
}

__device__ inline void dev_fine1(int b, int tid, const unsigned long long* __restrict__ sorted,
                                 const int* __restrict__ hist, const int* __restrict__ bsumA,
                                 int* __restrict__ rowptr, float* __restrict__ dinv,
                                 int* lh128, int* wtot) {
    if (tid < 128) lh128[tid] = 0;
    int s = hbase(hist, bsumA, b * NBE);
    int e = hbase(hist, bsumA, (b + 1) * NBE);
    __syncthreads();
    for (int p = s + tid; p < e; p += 256)
        atomicAdd(&lh128[(int)(unsigned)(sorted[p] >> 48) - b * 128], 1);  // LDS
    __syncthreads();
    int ln = tid & 63;
    int v = (tid < 128) ? lh128[tid] : 0;
    int xs = v;
    #pragma unroll
    for (int off = 1; off < 64; off <<= 1) {
        int t = __shfl_up(xs, off, 64);
        if (ln >= off) xs += t;
    }
    if (tid == 63) *wtot = xs;
    __syncthreads();
    int excl = xs - v + ((tid >= 64 && tid < 128) ? *wtot : 0);
    int gr = b * 128 + tid;
    if (tid < 128 && gr < NN) {
        rowptr[gr] = s + excl;
        dinv[gr] = v > 0 ? rsqrtf((float)v) : 0.f;
    }
    if (b == NBKT_REAL - 1 && tid == 0) rowptr[NN] = e;
}

__device__ inline void dev_fine2(int b, int tid, const unsigned long long* __restrict__ sorted,
                                 const int* __restrict__ hist, const int* __restrict__ bsumA,
                                 const int* __restrict__ rowptr, const float* __restrict__ dinv,
                                 unsigned* __restrict__ pairs, int* lrp, float* ldv) {
    int gr = b * 128 + tid;
    if (tid < 128) {
        lrp[tid] = (gr < NN) ? rowptr[gr] : 0;
        ldv[tid] = (gr < NN) ? dinv[gr] : 0.f;
    }
    int s = hbase(hist, bsumA, b * NBE);
    int e = hbase(hist, bsumA, (b + 1) * NBE);
    __syncthreads();
    for (int p = s + tid; p < e; p += 256) {
        unsigned long long it = sorted[p];
        int lr = (int)(unsigned)(it >> 48) - b * 128;
        unsigned c = (unsigned)(it >> 32) & 0xFFFFu;
        float w = __uint_as_float((unsigned)it);
        float lap = -ldv[lr] * dinv[c] * w;
        int slot = atomicAdd(&lrp[lr], 1);   // LDS
        bf16 lb = (bf16)lap;
        pairs[slot] = c | ((unsigned)*(unsigned short*)&lb << 16);
    }
}

template <int WRITEQ>
__device__ inline void dev_spmm(int t, const unsigned char* __restrict__ vq,
                                const int* __restrict__ rowptr, const unsigned* __restrict__ pairs,
                                bf16* __restrict__ y, unsigned char* __restrict__ yq) {
    int i = t / 9;
    int fo = (t - i * 9) * 16;
    const unsigned char* vp = vq + fo;

    float a[16];
    #pragma unroll
    for (int j = 0; j < 16; ++j) a[j] = 0.f;

    int s = rowptr[i], e = rowptr[i + 1];
    int p = s;
    for (; p + 1 < e; p += 2) {
        unsigned pr0 = pairs[p], pr1 = pairs[p + 1];
        uint4 u0 = *(const uint4*)(vp + (pr0 & 0xffffu) * FF);
        uint4 u1 = *(const uint4*)(vp + (pr1 & 0xffffu) * FF);
        fma16q(a, bhi(pr0), u0);
        fma16q(a, bhi(pr1), u1);
    }
    if (p < e) {
        unsigned pr = pairs[p];
        uint4 u = *(const uint4*)(vp + (pr & 0xffffu) * FF);
        fma16q(a, bhi(pr), u);
    }

    unsigned short hs[16];
    #pragma unroll
    for (int j = 0; j < 16; ++j) {
        bf16 b = (bf16)a[j];
        hs[j] = *(unsigned short*)&b;
    }
    uint4* yp = (uint4*)((unsigned short*)y + i * FF + fo);
    yp[0] = ((uint4*)hs)[0];
    yp[1] = ((uint4*)hs)[1];

    if (WRITEQ) {
        uint4 q;
        q.x = enc4(a[0], a[1], a[2], a[3]);
        q.y = enc4(a[4], a[5], a[6], a[7]);
        q.z = enc4(a[8], a[9], a[10], a[11]);
        q.w = enc4(a[12], a[13], a[14], a[15]);
        *(uint4*)(yq + i * FF + fo) = q;
    }
}

// ================= cooperative mega-kernel: 8 pipeline stages, 7 grid syncs =================

__global__ __launch_bounds__(256, 6)
void mega_k(const float* __restrict__ x, bf16* __restrict__ xb, unsigned char* __restrict__ xq,
            const int* __restrict__ ei, const float* __restrict__ ew,
            unsigned long long* __restrict__ items, int* __restrict__ hist,
            int* __restrict__ bsumA, const float* __restrict__ wt, short* __restrict__ wtb,
            unsigned long long* __restrict__ sorted, int* __restrict__ rowptr,
            float* __restrict__ dinv, unsigned* __restrict__ pairs,
            bf16* __restrict__ tx1, unsigned char* __restrict__ tx1q, bf16* __restrict__ tx2) {
    __shared__ int lh[NBUCKET];
    __shared__ int s128[128];
    __shared__ float f128[128];
    __shared__ int wsum[4], woff[4];
    __shared__ int wtot, nzf;
    cg::grid_group grid = cg::this_grid();
    int tid = threadIdx.x;
    int bid = blockIdx.x;

    // P0: cvt(x) | edge pack+hist | cvt+fold(W)
    for (int vb = bid; vb < NV0; vb += MGRID) {
        if (vb < CVTBLK)            dev_cvt(vb, tid, x, xb, xq);
        else if (vb < CVTBLK + NBE) dev_edge(vb - CVTBLK, tid, ei, ew, items, hist, lh, &nzf);
        else                        dev_cvtw(vb - CVTBLK - NBE, tid, wt, wtb);
    }
    grid.sync();
    // P1: scan level 1
    if (bid < SCANBLK) dev_scanA1(bid, tid, hist, bsumA, wsum, woff);
    grid.sync();
    // P2: scan level 2 (block 0)
    if (bid == 0) dev_scanA2(tid, bsumA, wsum, woff);
    grid.sync();
    // P3: partition scatter
    if (bid < NBE) dev_pscat(bid, tid, items, hist, bsumA, sorted, lh);
    grid.sync();
    // P4: per-bucket rowptr + dinv
    if (bid < NBKT_REAL) dev_fine1(bid, tid, sorted, hist, bsumA, rowptr, dinv, s128, &wtot);
    grid.sync();
    // P5: pairs in CSR order
    if (bid < NBKT_REAL) dev_fine2(bid, tid, sorted, hist, bsumA, rowptr, dinv, pairs, s128, f128);
    grid.sync();
    // P6: spmm pass 1 (xq -> tx1, tx1q)
    for (int vb = bid; vb < SPBLK; vb += MGRID) {
        int t = vb * 256 + tid;
        if (t < NN * 9) dev_spmm<1>(t, xq, rowptr, pairs, tx1, tx1q);
    }
    grid.sync();
    // P7: spmm pass 2 (tx1q -> tx2)
    for (int vb = bid; vb < SPBLK; vb += MGRID) {
        int t = vb * 256 + tid;
        if (t < NN * 9) dev_spmm<0>(t, tx1q, rowptr, pairs, tx2, (unsigned char*)0);
    }
}

// ================= fallback standalone kernels (identical semantics) =================

__global__ void fusedA_k(const float* __restrict__ x, bf16* __restrict__ xb,
                         unsigned char* __restrict__ xq,
                         const int* __restrict__ ei, const float* __restrict__ ew,
                         unsigned long long* __restrict__ items, int* __restrict__ hist,
                         const float* __restrict__ wt, short* __restrict__ wtb) {
    __shared__ int lh[NBUCKET];
    __shared__ int nzf;
    int b = blockIdx.x, tid = threadIdx.x;
    if (b < CVTBLK)            dev_cvt(b, tid, x, xb, xq);
    else if (b < CVTBLK + NBE) dev_edge(b - CVTBLK, tid, ei, ew, items, hist, lh, &nzf);
    else                       dev_cvtw(b - CVTBLK - NBE, tid, wt, wtb);
}

__global__ void scanA1_k(int* __restrict__ hist, int* __restrict__ bsumA) {
    __shared__ int wsum[4], woff[4];
    dev_scanA1(blockIdx.x, threadIdx.x, hist, bsumA, wsum, woff);
}

__global__ void scanA2_k(int* __restrict__ bsumA) {
    __shared__ int wsum[4], woff[4];
    dev_scanA2(threadIdx.x, bsumA, wsum, woff);
}

__global__ void pscat_k(const unsigned long long* __restrict__ items,
                        const int* __restrict__ hist, const int* __restrict__ bsumA,
                        unsigned long long* __restrict__ sorted) {
    __shared__ int lbase[NBUCKET];
    dev_pscat(blockIdx.x, threadIdx.x, items, hist, bsumA, sorted, lbase);
}

__global__ void fine1_k(const unsigned long long* __restrict__ sorted,
                        const int* __restrict__ hist, const int* __restrict__ bsumA,
                        int* __restrict__ rowptr, float* __restrict__ dinv) {
    __shared__ int lh128[128];
    __shared__ int wtot;
    dev_fine1(blockIdx.x, threadIdx.x, sorted, hist, bsumA, rowptr, dinv, lh128, &wtot);
}

__global__ void fine2_k(const unsigned long long* __restrict__ sorted,
                        const int* __restrict__ hist, const int* __restrict__ bsumA,
                        const int* __restrict__ rowptr, const float* __restrict__ dinv,
                        unsigned* __restrict__ pairs) {
    __shared__ int lrp[128];
    __shared__ float ldv[128];
    dev_fine2(blockIdx.x, threadIdx.x, sorted, hist, bsumA, rowptr, dinv, pairs, lrp, ldv);
}

template <int WRITEQ>
__global__ void spmm_k(const unsigned char* __restrict__ vq,
                       const int* __restrict__ rowptr, const unsigned* __restrict__ pairs,
                       bf16* __restrict__ y, unsigned char* __restrict__ yq) {
    int t = blockIdx.x * 256 + threadIdx.x;
    if (t >= NN * 9) return;
    dev_spmm<WRITEQ>(t, vq, rowptr, pairs, y, yq);
}

// ---------------- fused MFMA GEMM: full W resident in LDS, 1 block/CU, 16 waves ----------------

__global__ __launch_bounds__(1024)
void gemm_fused(const bf16* __restrict__ A0, const bf16* __restrict__ A1,
                const bf16* __restrict__ A2, const short* __restrict__ wtb,
                const float* __restrict__ bias, float* __restrict__ out) {
    __shared__ __align__(16) short Wt[3 * 144 * 168];   // 145,152 B
    int tid = threadIdx.x;

    {
        const uint4* Wg = (const uint4*)wtb;
        uint4* Wl = (uint4*)Wt;
        #pragma unroll
        for (int q = 0; q < 9; ++q) {
            int idx = q * 1024 + tid;
            if (idx < 9072) Wl[idx] = Wg[idx];
        }
    }
    __syncthreads();   // the ONLY barrier

    int wv = tid >> 6, ln = tid & 63;
    int m16 = ln & 15, quad = ln >> 4;
    int tile = wv * 256 + blockIdx.x;
    if (tile * 16 >= NN) return;
    int rowBase = tile * 16;
    int row = rowBase + m16;

    const bf16* const srcs[3] = {A0, A1, A2};
    const short8 zero8 = {0, 0, 0, 0, 0, 0, 0, 0};

    floatx4 acc[9];
    #pragma unroll
    for (int q = 0; q < 9; ++q) acc[q] = (floatx4){0.f, 0.f, 0.f, 0.f};

    #pragma unroll
    for (int ph = 0; ph < 3; ++ph) {
        const bf16* A = srcs[ph];
        short8 a[5];
        #pragma unroll
        for (int kt = 0; kt < 5; ++kt) {
            int k0 = kt * 32 + quad * 8;
            if (k0 < FF)
                a[kt] = *(const short8*)((const short*)A + row * FF + k0);
            else
                a[kt] = zero8;
        }

        const short* Wp = Wt + ph * 144 * 168;
        #pragma unroll
        for (int nt = 0; nt < 9; ++nt) {
            #pragma unroll
            for (int kt = 0; kt < 5; ++kt) {
                short8 b = *(const short8*)&Wp[(nt * 16 + m16) * 168 + kt * 32 + quad * 8];
                acc[nt] = __builtin_amdgcn_mfma_f32_16x16x32_bf16(a[kt], b, acc[nt], 0, 0, 0);
            }
        }
    }

    int rowc = rowBase + quad * 4;
    #pragma unroll
    for (int nt = 0; nt < 9; ++nt) {
        int col = nt * 16 + m16;
        float bs = bias[col];
        #pragma unroll
        for (int r = 0; r < 4; ++r) {
            int rr = rowc + r;
            out[rr * FF + col] = acc[nt][r] + bs;
        }
    }
}

// ---------------- launch ----------------

extern "C" void kernel_launch(void* const* d_in, const int* in_sizes, int n_in,
                              void* d_out, int out_size, void* d_ws, size_t ws_size,
                              hipStream_t stream) {
    int ix = -1, iei = -1, iew = -1, iwt = -1, ib = -1;
    for (int i = 0; i < n_in; ++i) {
        switch (in_sizes[i]) {
            case NN * FF:      if (ix  < 0) ix  = i; break;
            case 2 * EE:       if (iei < 0) iei = i; break;
            case EE:           if (iew < 0) iew = i; break;
            case 3 * FF * FF:  if (iwt < 0) iwt = i; break;
            case FF:           if (ib  < 0) ib  = i; break;
        }
    }
    if (ix < 0 || iei < 0 || iew < 0 || iwt < 0 || ib < 0) {
        ix = 0; iei = 1; iew = 2; iwt = 3; ib = 4;
    }
    const float* x    = (const float*)d_in[ix];
    const int*   ei   = (const int*)d_in[iei];
    const float* ew   = (const float*)d_in[iew];
    const float* wt   = (const float*)d_in[iwt];
    const float* bias = (const float*)d_in[ib];
    float* out = (float*)d_out;

    char* p = (char*)d_ws;
    unsigned long long* items  = (unsigned long long*)(p + 0);          // 6.4 MB
    unsigned long long* sorted = (unsigned long long*)(p + 6400000);    // 6.4 MB
    int*      hist   = (int*)(p + 12800000);             // HM ints = 613 KB
    int*      bsumA  = (int*)(p + 13500000);             // SCANBLK ints
    int*      rowptr = (int*)(p + 13600000);             // N+1 ints
    float*    dinv   = (float*)(p + 13900000);           // N floats
    unsigned* pairs  = (unsigned*)(p + 14200000);        // E words = 3.2 MB
    short*    wtb    = (short*)(p + 17500000);           // 145,152 B
    bf16*     tx1    = (bf16*)(p + 17700000);            // 14.4 MB
    bf16*     tx2    = (bf16*)(p + 32100000);            // 14.4 MB
    unsigned char* xq   = (unsigned char*)(p + 46500000); // 7.2 MB
    unsigned char* tx1q = (unsigned char*)(p + 53700000); // 7.2 MB
    bf16*     xb     = (bf16*)(p + 60900000);            // 14.4 MB -> ends 75,300,000

    if (ws_size < 75300000) return;

    // one-time: can mega_k run cooperatively at MGRID (6 blocks/CU on 256 CUs)?
    static int s_coop = -1;
    if (s_coop < 0) {
        int nb = 0;
        hipError_t oe = hipOccupancyMaxActiveBlocksPerMultiprocessor(&nb, mega_k, 256, 0);
        s_coop = (oe == hipSuccess && nb >= MGRID / 256) ? 1 : 0;
    }

    int launched = 0;
    if (s_coop) {
        void* args[] = {(void*)&x, (void*)&xb, (void*)&xq, (void*)&ei, (void*)&ew,
                        (void*)&items, (void*)&hist, (void*)&bsumA, (void*)&wt, (void*)&wtb,
                        (void*)&sorted, (void*)&rowptr, (void*)&dinv, (void*)&pairs,
                        (void*)&tx1, (void*)&tx1q, (void*)&tx2};
        hipError_t e = hipLaunchCooperativeKernel(mega_k, dim3(MGRID), dim3(256),
                                                  args, 0, stream);
        if (e == hipSuccess) launched = 1;
        else s_coop = 0;
    }
    if (!launched) {
        // fallback: 8-kernel chain (identical semantics)
        int spGrid = (NN * 9 + 255) / 256;
        fusedA_k<<<NV0, 256, 0, stream>>>(x, xb, xq, ei, ew, items, hist, wt, wtb);
        scanA1_k<<<SCANBLK, 256, 0, stream>>>(hist, bsumA);
        scanA2_k<<<1, 256, 0, stream>>>(bsumA);
        pscat_k<<<NBE, 256, 0, stream>>>(items, hist, bsumA, sorted);
        fine1_k<<<NBKT_REAL, 256, 0, stream>>>(sorted, hist, bsumA, rowptr, dinv);
        fine2_k<<<NBKT_REAL, 256, 0, stream>>>(sorted, hist, bsumA, rowptr, dinv, pairs);
        spmm_k<1><<<spGrid, 256, 0, stream>>>(xq, rowptr, pairs, tx1, tx1q);
        spmm_k<0><<<spGrid, 256, 0, stream>>>(tx1q, rowptr, pairs, tx2, (unsigned char*)0);
    }

    gemm_fused<<<256, 1024, 0, stream>>>(xb, tx1, tx2, wtb, bias, out);
}